// Round 1
// baseline (11809.771 us; speedup 1.0000x reference)
//
#include <hip/hip_runtime.h>
#include <hip/hip_bf16.h>
#include <stdint.h>

#define HH   512
#define VV   32000
#define T1N  128
#define T2N  64
#define BB   32
#define NBLK_REC 192

typedef __attribute__((ext_vector_type(8))) short short8;
typedef __attribute__((ext_vector_type(4))) float f32x4;

__device__ __forceinline__ ushort f2b(float f) {
  unsigned u = __float_as_uint(f);
  unsigned r = (u + 0x7fffu + ((u >> 16) & 1u)) >> 16;
  return (ushort)r;
}
__device__ __forceinline__ float blo(unsigned u){ return __uint_as_float(u << 16); }
__device__ __forceinline__ float bhi(unsigned u){ return __uint_as_float(u & 0xffff0000u); }

__device__ __forceinline__ float fast_tanh(float x) {
  float ax = fabsf(x);
  float e  = __expf(-2.f * ax);
  float t  = (1.f - e) / (1.f + e);
  return x < 0.f ? -t : t;
}
__device__ __forceinline__ float fsig(float x) { return 1.f / (1.f + __expf(-x)); }

// ---------------- conversions ----------------
__global__ __launch_bounds__(256) void k_cvt(const float* __restrict__ s, ushort* __restrict__ d, int n) {
  int i = (blockIdx.x * 256 + threadIdx.x) * 4;
  if (i < n) {
    float4 v = *(const float4*)(s + i);
    ushort4 o = { f2b(v.x), f2b(v.y), f2b(v.z), f2b(v.w) };
    *(ushort4*)(d + i) = o;
  }
}

// wa_W (512,1024) -> WxB = wa_W[:, :512], WeB = wa_W[:, 512:]
__global__ __launch_bounds__(256) void k_cvt_wa(const float* __restrict__ wa,
                                                ushort* __restrict__ Wx, ushort* __restrict__ We) {
  int i = (blockIdx.x * 256 + threadIdx.x) * 4;   // 0..524284
  int half = (i >= HH * HH);
  int j = i & (HH * HH - 1);
  int o = j >> 9, c = j & 511;
  const float* s = wa + (size_t)o * 1024 + c + (half ? 512 : 0);
  float4 v = *(const float4*)s;
  ushort4 ov = { f2b(v.x), f2b(v.y), f2b(v.z), f2b(v.w) };
  *(ushort4*)((half ? We : Wx) + j) = ov;
}

// x = emb[toks] -> bf16 into ginB[:, 0:512] (row stride 1024)
__global__ __launch_bounds__(256) void k_embed(const int* __restrict__ toks, const float* __restrict__ emb,
                                               ushort* __restrict__ ginB) {
  int i = (blockIdx.x * 256 + threadIdx.x) * 4;   // over T2*B*512
  int row = i >> 9, c = i & 511;
  int tok = toks[row];
  float4 v = *(const float4*)(emb + (size_t)tok * HH + c);
  ushort4 ov = { f2b(v.x), f2b(v.y), f2b(v.z), f2b(v.w) };
  *(ushort4*)(ginB + (size_t)row * 1024 + c) = ov;
}

__global__ __launch_bounds__(256) void k_init_h(const float* __restrict__ st,
                                                float* __restrict__ h0g, float* __restrict__ h1g) {
  int i = blockIdx.x * 256 + threadIdx.x;  // 16384
  h0g[i] = st[i];
  h1g[i] = st[BB * HH + i];
}

// ---------------- bf16 MFMA GEMM:  C[m,n] = sum_k A[m,k]*B[n,k] (+bias[n]) ----------------
// A: M x K bf16 rows (row stride lda), B: N x K bf16 row-major, C fp32 (ldc).
// Grid: (N/128, M/128), 256 threads. BK=32.
__global__ __launch_bounds__(256) void k_gemm(const ushort* __restrict__ A, int lda,
                                              const ushort* __restrict__ B,
                                              const float* __restrict__ bias,
                                              float* __restrict__ C, int ldc, int K) {
  __shared__ ushort sA[128 * 32];
  __shared__ ushort sB[128 * 32];
  const int tid  = threadIdx.x;
  const int bm   = blockIdx.y * 128;
  const int bn   = blockIdx.x * 128;
  const int lane = tid & 63;
  const int wave = tid >> 6;
  const int wm   = (wave >> 1) * 64;
  const int wn   = (wave & 1) * 64;
  const int m16  = lane & 15;
  const int quad = lane >> 4;

  f32x4 acc[4][4] = {};

  for (int k0 = 0; k0 < K; k0 += 32) {
#pragma unroll
    for (int q = 0; q < 2; ++q) {
      int idx = q * 256 + tid;
      int row = idx >> 2;
      int kc  = (idx & 3) << 3;
      uint4 va = *(const uint4*)(A + (size_t)(bm + row) * lda + k0 + kc);
      *(uint4*)(&sA[idx * 8]) = va;
      uint4 vb = *(const uint4*)(B + (size_t)(bn + row) * K + k0 + kc);
      *(uint4*)(&sB[idx * 8]) = vb;
    }
    __syncthreads();
    short8 a[4], b[4];
#pragma unroll
    for (int i = 0; i < 4; ++i)
      a[i] = *(const short8*)(&sA[(wm + i * 16 + m16) * 32 + quad * 8]);
#pragma unroll
    for (int j = 0; j < 4; ++j)
      b[j] = *(const short8*)(&sB[(wn + j * 16 + m16) * 32 + quad * 8]);
#pragma unroll
    for (int i = 0; i < 4; ++i)
#pragma unroll
      for (int j = 0; j < 4; ++j)
        acc[i][j] = __builtin_amdgcn_mfma_f32_16x16x32_bf16(a[i], b[j], acc[i][j], 0, 0, 0);
    __syncthreads();
  }
  // C/D layout: col = lane&15, row = quad*4 + reg
#pragma unroll
  for (int i = 0; i < 4; ++i) {
    int gm = bm + wm + i * 16 + quad * 4;
#pragma unroll
    for (int j = 0; j < 4; ++j) {
      int gn = bn + wn + j * 16 + m16;
      float bv = bias ? bias[gn] : 0.f;
#pragma unroll
      for (int r = 0; r < 4; ++r)
        C[(size_t)(gm + r) * ldc + gn] = acc[i][j][r] + bv;
    }
  }
}

// ---------------- attention scores: e[t2,b,t1] = sum_h tanh(xproj[t2,b,h]+encp[t1,b,h])*va[h] ----------------
// grid 512 = (16 t2-groups of 4) x 32 b, 256 threads (4 waves)
__global__ __launch_bounds__(256) void k_scores(const float* __restrict__ xproj,
                                                const float* __restrict__ encp,
                                                const float* __restrict__ vaW,
                                                float* __restrict__ e) {
  int t2g = blockIdx.x >> 5;
  int b   = blockIdx.x & 31;
  __shared__ float sx[4][512];
  int tid = threadIdx.x;
  for (int i = tid; i < 4 * 512; i += 256) {
    int tt = i >> 9, h = i & 511;
    sx[tt][h] = xproj[((size_t)(t2g * 4 + tt) * BB + b) * HH + h];
  }
  __syncthreads();
  int lane = tid & 63, w = tid >> 6;
  int h8 = lane * 8;
  float va[8];
#pragma unroll
  for (int j = 0; j < 8; ++j) va[j] = vaW[h8 + j];
  for (int t1 = w; t1 < T1N; t1 += 4) {
    const float* ep = encp + ((size_t)t1 * BB + b) * HH + h8;
    float ev[8];
    *(float4*)&ev[0] = *(const float4*)ep;
    *(float4*)&ev[4] = *(const float4*)(ep + 4);
    float s0 = 0, s1 = 0, s2 = 0, s3 = 0;
#pragma unroll
    for (int j = 0; j < 8; ++j) {
      float epj = ev[j], vj = va[j];
      s0 += fast_tanh(sx[0][h8 + j] + epj) * vj;
      s1 += fast_tanh(sx[1][h8 + j] + epj) * vj;
      s2 += fast_tanh(sx[2][h8 + j] + epj) * vj;
      s3 += fast_tanh(sx[3][h8 + j] + epj) * vj;
    }
#pragma unroll
    for (int off = 32; off; off >>= 1) {
      s0 += __shfl_down(s0, off);
      s1 += __shfl_down(s1, off);
      s2 += __shfl_down(s2, off);
      s3 += __shfl_down(s3, off);
    }
    if (lane == 0) {
      size_t base = ((size_t)(t2g * 4) * BB + b) * T1N + t1;
      e[base]                 = s0;
      e[base + 1 * BB * T1N]  = s1;
      e[base + 2 * BB * T1N]  = s2;
      e[base + 3 * BB * T1N]  = s3;
    }
  }
}

// softmax over t1 (rows of 128); row = t2*32+b; also emits last_score output (T1,B,1)
__global__ __launch_bounds__(128) void k_softmax(const float* __restrict__ e, float* __restrict__ score,
                                                 float* __restrict__ out_last) {
  int row = blockIdx.x;
  int tid = threadIdx.x;
  float v = e[(size_t)row * T1N + tid];
  __shared__ float red[128];
  red[tid] = v; __syncthreads();
  for (int s = 64; s; s >>= 1) { if (tid < s) red[tid] = fmaxf(red[tid], red[tid + s]); __syncthreads(); }
  float mx = red[0]; __syncthreads();
  float p = __expf(v - mx);
  red[tid] = p; __syncthreads();
  for (int s = 64; s; s >>= 1) { if (tid < s) red[tid] += red[tid + s]; __syncthreads(); }
  float sc = p / red[0];
  score[(size_t)row * T1N + tid] = sc;
  if ((row >> 5) == T2N - 1) out_last[tid * BB + (row & 31)] = sc;
}

// att_v[t2,b,h] = sum_t1 enc[t1,b,h]*score[t2,b,t1] -> bf16 into ginB[:,512:1024]
// grid 256 = (8 t2-groups of 8) x 32 b, 256 threads (each 2 h)
__global__ __launch_bounds__(256) void k_attv(const float* __restrict__ enc, const float* __restrict__ score,
                                              ushort* __restrict__ ginB) {
  int t2g = blockIdx.x >> 5;
  int b   = blockIdx.x & 31;
  __shared__ float ssc[8][T1N];
  int tid = threadIdx.x;
  for (int i = tid; i < 8 * T1N; i += 256) {
    int j = i >> 7, t1 = i & 127;
    ssc[j][t1] = score[((size_t)(t2g * 8 + j) * BB + b) * T1N + t1];
  }
  __syncthreads();
  float a0[8] = {}, a1[8] = {};
  for (int t1 = 0; t1 < T1N; ++t1) {
    const float* er = enc + ((size_t)t1 * BB + b) * HH;
    float e0 = er[tid], e1 = er[tid + 256];
#pragma unroll
    for (int j = 0; j < 8; ++j) { a0[j] += e0 * ssc[j][t1]; a1[j] += e1 * ssc[j][t1]; }
  }
#pragma unroll
  for (int j = 0; j < 8; ++j) {
    size_t r = (size_t)(t2g * 8 + j) * BB + b;
    ginB[r * 1024 + 512 + tid]       = f2b(a0[j]);
    ginB[r * 1024 + 512 + tid + 256] = f2b(a1[j]);
  }
}

// ---------------- recurrence ----------------
__device__ __forceinline__ float dot512(const ushort* __restrict__ w, const float* __restrict__ h) {
  float s = 0.f;
#pragma unroll 8
  for (int k = 0; k < 512; k += 8) {
    uint4 wv = *(const uint4*)(w + k);
    float4 ha = *(const float4*)(h + k);
    float4 hb = *(const float4*)(h + k + 4);
    s += blo(wv.x) * ha.x + bhi(wv.x) * ha.y
       + blo(wv.y) * ha.z + bhi(wv.y) * ha.w
       + blo(wv.z) * hb.x + bhi(wv.z) * hb.y
       + blo(wv.w) * hb.z + bhi(wv.w) * hb.w;
  }
  return s;
}

__device__ __forceinline__ void gbar(unsigned* bar) {
  __threadfence();                 // agent-scope release (per-wave store drain + cache ops)
  __syncthreads();
  if (threadIdx.x == 0) {
    unsigned g = __hip_atomic_load(bar + 1, __ATOMIC_RELAXED, __HIP_MEMORY_SCOPE_AGENT);
    unsigned old = __hip_atomic_fetch_add(bar, 1u, __ATOMIC_ACQ_REL, __HIP_MEMORY_SCOPE_AGENT);
    if (old == NBLK_REC - 1) {
      __hip_atomic_store(bar, 0u, __ATOMIC_RELAXED, __HIP_MEMORY_SCOPE_AGENT);
      __hip_atomic_fetch_add(bar + 1, 1u, __ATOMIC_RELEASE, __HIP_MEMORY_SCOPE_AGENT);
    } else {
      while (__hip_atomic_load(bar + 1, __ATOMIC_ACQUIRE, __HIP_MEMORY_SCOPE_AGENT) == g)
        __builtin_amdgcn_s_sleep(1);
    }
  }
  __syncthreads();
  __threadfence();                 // acquire side for every wave
}

// grid 192 = 4 b-groups(8) x 48 n-groups, 256 threads
__global__ __launch_bounds__(256) void k_recur(
    const ushort* __restrict__ Whh0, const ushort* __restrict__ Wih1, const ushort* __restrict__ Whh1,
    const float* __restrict__ bhh0, const float* __restrict__ bih1, const float* __restrict__ bhh1,
    const float* __restrict__ gi0,
    float* __restrict__ gh0, float* __restrict__ gh1, float* __restrict__ gi1,
    float* __restrict__ h0g, float* __restrict__ h1g,
    ushort* __restrict__ ysB, float* __restrict__ out_h, unsigned* bar) {
  const int tid = threadIdx.x;
  const int bg = blockIdx.x / 48;
  const int ng = blockIdx.x % 48;
  const int b0 = bg * 8;
  const int n0 = ng * 64;
  __shared__ float sh0[8 * 516];
  __shared__ float sh1[8 * 516];
  const int gt = blockIdx.x * 256 + tid;

  for (int t = 0; t < T2N; ++t) {
    for (int i = tid; i < 8 * 512; i += 256) {
      int b = i >> 9, k = i & 511;
      sh0[b * 516 + k] = h0g[b0 * 512 + i];
      sh1[b * 516 + k] = h1g[b0 * 512 + i];
    }
    __syncthreads();
    // S1: gh0, gh1
#pragma unroll
    for (int q = 0; q < 2; ++q) {
      int d = q * 256 + tid;
      int b = d & 7;
      int n = n0 + (d >> 3);
      if (n < 1536) {
        float s = bhh0[n] + dot512(Whh0 + (size_t)n * 512, sh0 + b * 516);
        gh0[(b0 + b) * 1536 + n] = s;
      } else {
        int n2 = n - 1536;
        float s = bhh1[n2] + dot512(Whh1 + (size_t)n2 * 512, sh1 + b * 516);
        gh1[(b0 + b) * 1536 + n2] = s;
      }
    }
    gbar(bar);
    // S2: h0 update
    if (gt < 16384) {
      int b = gt >> 9, k = gt & 511;
      const float* g0 = gi0 + ((size_t)t * BB + b) * 1536;
      float r  = fsig(g0[k]        + gh0[b * 1536 + k]);
      float z  = fsig(g0[k + 512]  + gh0[b * 1536 + k + 512]);
      float nn = fast_tanh(g0[k + 1024] + r * gh0[b * 1536 + k + 1024]);
      h0g[b * 512 + k] = (1.f - z) * nn + z * h0g[b * 512 + k];
    }
    gbar(bar);
    // S3: gi1 (restage h0)
    for (int i = tid; i < 8 * 512; i += 256) {
      int b = i >> 9, k = i & 511;
      sh0[b * 516 + k] = h0g[b0 * 512 + i];
    }
    __syncthreads();
    {
      int b = tid & 7;
      int n = ng * 32 + (tid >> 3);
      float s = bih1[n] + dot512(Wih1 + (size_t)n * 512, sh0 + b * 516);
      gi1[(b0 + b) * 1536 + n] = s;
    }
    gbar(bar);
    // S4: h1 update + ys
    if (gt < 16384) {
      int b = gt >> 9, k = gt & 511;
      float r  = fsig(gi1[b * 1536 + k]       + gh1[b * 1536 + k]);
      float z  = fsig(gi1[b * 1536 + k + 512] + gh1[b * 1536 + k + 512]);
      float nn = fast_tanh(gi1[b * 1536 + k + 1024] + r * gh1[b * 1536 + k + 1024]);
      float hn = (1.f - z) * nn + z * h1g[b * 512 + k];
      h1g[b * 512 + k] = hn;
      ysB[((size_t)t * BB + b) * 512 + k] = f2b(hn);
    }
    gbar(bar);
  }
  if (gt < 16384) {
    out_h[gt]          = h0g[gt];
    out_h[16384 + gt]  = h1g[gt];
  }
}

// ---------------- launch ----------------
extern "C" void kernel_launch(void* const* d_in, const int* in_sizes, int n_in,
                              void* d_out, int out_size, void* d_ws, size_t ws_size,
                              hipStream_t stream) {
  const int*   toks  = (const int*)d_in[0];
  const float* state = (const float*)d_in[1];
  const float* enc   = (const float*)d_in[2];
  const float* emb   = (const float*)d_in[3];
  const float* wa_W  = (const float*)d_in[4];
  const float* wa_b  = (const float*)d_in[5];
  const float* va    = (const float*)d_in[6];
  const float* W_ih0 = (const float*)d_in[7];
  const float* W_hh0 = (const float*)d_in[8];
  const float* b_ih0 = (const float*)d_in[9];
  const float* b_hh0 = (const float*)d_in[10];
  const float* W_ih1 = (const float*)d_in[11];
  const float* W_hh1 = (const float*)d_in[12];
  const float* b_ih1 = (const float*)d_in[13];
  const float* b_hh1 = (const float*)d_in[14];
  const float* out_W = (const float*)d_in[15];
  const float* out_b = (const float*)d_in[16];

  float* y_out  = (float*)d_out;
  float* h_out  = y_out + (size_t)T2N * BB * VV;
  float* ls_out = h_out + 2 * BB * HH;

  char* ws = (char*)d_ws;
  size_t off = 0;
  auto alloc = [&](size_t bytes) -> void* {
    void* p = ws + off;
    off += (bytes + 255) & ~(size_t)255;
    return p;
  };
  unsigned* bar  = (unsigned*)alloc(256);
  ushort* encB   = (ushort*)alloc((size_t)T1N * BB * HH * 2);
  ushort* ginB   = (ushort*)alloc((size_t)T2N * BB * 2 * HH * 2);
  ushort* WeB    = (ushort*)alloc((size_t)HH * HH * 2);
  ushort* WxB    = (ushort*)alloc((size_t)HH * HH * 2);
  ushort* Wih0B  = (ushort*)alloc((size_t)3 * HH * 2 * HH * 2);
  ushort* Whh0B  = (ushort*)alloc((size_t)3 * HH * HH * 2);
  ushort* Wih1B  = (ushort*)alloc((size_t)3 * HH * HH * 2);
  ushort* Whh1B  = (ushort*)alloc((size_t)3 * HH * HH * 2);
  ushort* outWB  = (ushort*)alloc((size_t)VV * HH * 2);
  float* encproj = (float*)alloc((size_t)T1N * BB * HH * 4);
  float* xproj   = (float*)alloc((size_t)T2N * BB * HH * 4);
  float* eM      = (float*)alloc((size_t)T2N * BB * T1N * 4);
  float* score   = (float*)alloc((size_t)T2N * BB * T1N * 4);
  float* gi0     = (float*)alloc((size_t)T2N * BB * 3 * HH * 4);
  float* gh0     = (float*)alloc((size_t)BB * 3 * HH * 4);
  float* gh1     = (float*)alloc((size_t)BB * 3 * HH * 4);
  float* gi1     = (float*)alloc((size_t)BB * 3 * HH * 4);
  float* h0g     = (float*)alloc((size_t)BB * HH * 4);
  float* h1g     = (float*)alloc((size_t)BB * HH * 4);
  ushort* ysB    = (ushort*)alloc((size_t)T2N * BB * HH * 2);

  hipMemsetAsync(bar, 0, 256, stream);

  k_cvt<<<VV * HH / 1024, 256, 0, stream>>>(out_W, outWB, VV * HH);
  k_cvt<<<T1N * BB * HH / 1024, 256, 0, stream>>>(enc, encB, T1N * BB * HH);
  k_cvt<<<3 * HH * 2 * HH / 1024, 256, 0, stream>>>(W_ih0, Wih0B, 3 * HH * 2 * HH);
  k_cvt<<<3 * HH * HH / 1024, 256, 0, stream>>>(W_hh0, Whh0B, 3 * HH * HH);
  k_cvt<<<3 * HH * HH / 1024, 256, 0, stream>>>(W_ih1, Wih1B, 3 * HH * HH);
  k_cvt<<<3 * HH * HH / 1024, 256, 0, stream>>>(W_hh1, Whh1B, 3 * HH * HH);
  k_cvt_wa<<<2 * HH * HH / 1024, 256, 0, stream>>>(wa_W, WxB, WeB);
  k_embed<<<T2N * BB * HH / 1024, 256, 0, stream>>>(toks, emb, ginB);

  k_gemm<<<dim3(HH / 128, T1N * BB / 128), 256, 0, stream>>>(encB, HH, WeB, wa_b, encproj, HH, HH);
  k_gemm<<<dim3(HH / 128, T2N * BB / 128), 256, 0, stream>>>(ginB, 2 * HH, WxB, nullptr, xproj, HH, HH);

  k_scores<<<512, 256, 0, stream>>>(xproj, encproj, va, eM);
  k_softmax<<<T2N * BB, 128, 0, stream>>>(eM, score, ls_out);
  k_attv<<<256, 256, 0, stream>>>(enc, score, ginB);

  k_gemm<<<dim3(3 * HH / 128, T2N * BB / 128), 256, 0, stream>>>(ginB, 2 * HH, Wih0B, b_ih0, gi0, 3 * HH, 2 * HH);

  k_init_h<<<BB * HH / 256, 256, 0, stream>>>(state, h0g, h1g);
  k_recur<<<NBLK_REC, 256, 0, stream>>>(Whh0B, Wih1B, Whh1B, b_hh0, b_ih1, b_hh1,
                                        gi0, gh0, gh1, gi1, h0g, h1g, ysB, h_out, bar);

  k_gemm<<<dim3(VV / 128, T2N * BB / 128), 256, 0, stream>>>(ysB, HH, outWB, out_b, y_out, VV, HH);
}

// Round 2
// 3879.483 us; speedup vs baseline: 3.0442x; 3.0442x over previous
//
#include <hip/hip_runtime.h>
#include <hip/hip_bf16.h>
#include <stdint.h>

#define HH   512
#define VV   32000
#define T1N  128
#define T2N  64
#define BB   32

typedef __attribute__((ext_vector_type(8))) short short8;
typedef __attribute__((ext_vector_type(4))) float f32x4;

__device__ __forceinline__ ushort f2b(float f) {
  unsigned u = __float_as_uint(f);
  unsigned r = (u + 0x7fffu + ((u >> 16) & 1u)) >> 16;
  return (ushort)r;
}
__device__ __forceinline__ float blo(unsigned u){ return __uint_as_float(u << 16); }
__device__ __forceinline__ float bhi(unsigned u){ return __uint_as_float(u & 0xffff0000u); }

__device__ __forceinline__ float fast_tanh(float x) {
  float ax = fabsf(x);
  float e  = __expf(-2.f * ax);
  float t  = (1.f - e) / (1.f + e);
  return x < 0.f ? -t : t;
}
__device__ __forceinline__ float fsig(float x) { return 1.f / (1.f + __expf(-x)); }

// ---------------- conversions ----------------
__global__ __launch_bounds__(256) void k_cvt(const float* __restrict__ s, ushort* __restrict__ d, int n) {
  int i = (blockIdx.x * 256 + threadIdx.x) * 4;
  if (i < n) {
    float4 v = *(const float4*)(s + i);
    ushort4 o = { f2b(v.x), f2b(v.y), f2b(v.z), f2b(v.w) };
    *(ushort4*)(d + i) = o;
  }
}

// wa_W (512,1024) -> WxB = wa_W[:, :512], WeB = wa_W[:, 512:]
__global__ __launch_bounds__(256) void k_cvt_wa(const float* __restrict__ wa,
                                                ushort* __restrict__ Wx, ushort* __restrict__ We) {
  int i = (blockIdx.x * 256 + threadIdx.x) * 4;
  int half = (i >= HH * HH);
  int j = i & (HH * HH - 1);
  int o = j >> 9, c = j & 511;
  const float* s = wa + (size_t)o * 1024 + c + (half ? 512 : 0);
  float4 v = *(const float4*)s;
  ushort4 ov = { f2b(v.x), f2b(v.y), f2b(v.z), f2b(v.w) };
  *(ushort4*)((half ? We : Wx) + j) = ov;
}

// x = emb[toks] -> bf16 into ginB[:, 0:512] (row stride 1024)
__global__ __launch_bounds__(256) void k_embed(const int* __restrict__ toks, const float* __restrict__ emb,
                                               ushort* __restrict__ ginB) {
  int i = (blockIdx.x * 256 + threadIdx.x) * 4;
  int row = i >> 9, c = i & 511;
  int tok = toks[row];
  float4 v = *(const float4*)(emb + (size_t)tok * HH + c);
  ushort4 ov = { f2b(v.x), f2b(v.y), f2b(v.z), f2b(v.w) };
  *(ushort4*)(ginB + (size_t)row * 1024 + c) = ov;
}

// ---------------- bf16 MFMA GEMM (fp32 out) ----------------
__global__ __launch_bounds__(256) void k_gemm(const ushort* __restrict__ A, int lda,
                                              const ushort* __restrict__ B,
                                              const float* __restrict__ bias,
                                              float* __restrict__ C, int ldc, int K) {
  __shared__ ushort sA[128 * 32];
  __shared__ ushort sB[128 * 32];
  const int tid  = threadIdx.x;
  const int bm   = blockIdx.y * 128;
  const int bn   = blockIdx.x * 128;
  const int lane = tid & 63;
  const int wave = tid >> 6;
  const int wm   = (wave >> 1) * 64;
  const int wn   = (wave & 1) * 64;
  const int m16  = lane & 15;
  const int quad = lane >> 4;

  f32x4 acc[4][4] = {};

  for (int k0 = 0; k0 < K; k0 += 32) {
#pragma unroll
    for (int q = 0; q < 2; ++q) {
      int idx = q * 256 + tid;
      int row = idx >> 2;
      int kc  = (idx & 3) << 3;
      uint4 va = *(const uint4*)(A + (size_t)(bm + row) * lda + k0 + kc);
      *(uint4*)(&sA[idx * 8]) = va;
      uint4 vb = *(const uint4*)(B + (size_t)(bn + row) * K + k0 + kc);
      *(uint4*)(&sB[idx * 8]) = vb;
    }
    __syncthreads();
    short8 a[4], b[4];
#pragma unroll
    for (int i = 0; i < 4; ++i)
      a[i] = *(const short8*)(&sA[(wm + i * 16 + m16) * 32 + quad * 8]);
#pragma unroll
    for (int j = 0; j < 4; ++j)
      b[j] = *(const short8*)(&sB[(wn + j * 16 + m16) * 32 + quad * 8]);
#pragma unroll
    for (int i = 0; i < 4; ++i)
#pragma unroll
      for (int j = 0; j < 4; ++j)
        acc[i][j] = __builtin_amdgcn_mfma_f32_16x16x32_bf16(a[i], b[j], acc[i][j], 0, 0, 0);
    __syncthreads();
  }
#pragma unroll
  for (int i = 0; i < 4; ++i) {
    int gm = bm + wm + i * 16 + quad * 4;
#pragma unroll
    for (int j = 0; j < 4; ++j) {
      int gn = bn + wn + j * 16 + m16;
      float bv = bias ? bias[gn] : 0.f;
#pragma unroll
      for (int r = 0; r < 4; ++r)
        C[(size_t)(gm + r) * ldc + gn] = acc[i][j][r] + bv;
    }
  }
}

// same GEMM but bf16 output (for gi0)
__global__ __launch_bounds__(256) void k_gemm_b16(const ushort* __restrict__ A, int lda,
                                                  const ushort* __restrict__ B,
                                                  const float* __restrict__ bias,
                                                  ushort* __restrict__ C, int ldc, int K) {
  __shared__ ushort sA[128 * 32];
  __shared__ ushort sB[128 * 32];
  const int tid  = threadIdx.x;
  const int bm   = blockIdx.y * 128;
  const int bn   = blockIdx.x * 128;
  const int lane = tid & 63;
  const int wave = tid >> 6;
  const int wm   = (wave >> 1) * 64;
  const int wn   = (wave & 1) * 64;
  const int m16  = lane & 15;
  const int quad = lane >> 4;

  f32x4 acc[4][4] = {};

  for (int k0 = 0; k0 < K; k0 += 32) {
#pragma unroll
    for (int q = 0; q < 2; ++q) {
      int idx = q * 256 + tid;
      int row = idx >> 2;
      int kc  = (idx & 3) << 3;
      uint4 va = *(const uint4*)(A + (size_t)(bm + row) * lda + k0 + kc);
      *(uint4*)(&sA[idx * 8]) = va;
      uint4 vb = *(const uint4*)(B + (size_t)(bn + row) * K + k0 + kc);
      *(uint4*)(&sB[idx * 8]) = vb;
    }
    __syncthreads();
    short8 a[4], b[4];
#pragma unroll
    for (int i = 0; i < 4; ++i)
      a[i] = *(const short8*)(&sA[(wm + i * 16 + m16) * 32 + quad * 8]);
#pragma unroll
    for (int j = 0; j < 4; ++j)
      b[j] = *(const short8*)(&sB[(wn + j * 16 + m16) * 32 + quad * 8]);
#pragma unroll
    for (int i = 0; i < 4; ++i)
#pragma unroll
      for (int j = 0; j < 4; ++j)
        acc[i][j] = __builtin_amdgcn_mfma_f32_16x16x32_bf16(a[i], b[j], acc[i][j], 0, 0, 0);
    __syncthreads();
  }
#pragma unroll
  for (int i = 0; i < 4; ++i) {
    int gm = bm + wm + i * 16 + quad * 4;
#pragma unroll
    for (int j = 0; j < 4; ++j) {
      int gn = bn + wn + j * 16 + m16;
      float bv = bias ? bias[gn] : 0.f;
#pragma unroll
      for (int r = 0; r < 4; ++r)
        C[(size_t)(gm + r) * ldc + gn] = f2b(acc[i][j][r] + bv);
    }
  }
}

// ---------------- attention ----------------
__global__ __launch_bounds__(256) void k_scores(const float* __restrict__ xproj,
                                                const float* __restrict__ encp,
                                                const float* __restrict__ vaW,
                                                float* __restrict__ e) {
  int t2g = blockIdx.x >> 5;
  int b   = blockIdx.x & 31;
  __shared__ float sx[4][512];
  int tid = threadIdx.x;
  for (int i = tid; i < 4 * 512; i += 256) {
    int tt = i >> 9, h = i & 511;
    sx[tt][h] = xproj[((size_t)(t2g * 4 + tt) * BB + b) * HH + h];
  }
  __syncthreads();
  int lane = tid & 63, w = tid >> 6;
  int h8 = lane * 8;
  float va[8];
#pragma unroll
  for (int j = 0; j < 8; ++j) va[j] = vaW[h8 + j];
  for (int t1 = w; t1 < T1N; t1 += 4) {
    const float* ep = encp + ((size_t)t1 * BB + b) * HH + h8;
    float ev[8];
    *(float4*)&ev[0] = *(const float4*)ep;
    *(float4*)&ev[4] = *(const float4*)(ep + 4);
    float s0 = 0, s1 = 0, s2 = 0, s3 = 0;
#pragma unroll
    for (int j = 0; j < 8; ++j) {
      float epj = ev[j], vj = va[j];
      s0 += fast_tanh(sx[0][h8 + j] + epj) * vj;
      s1 += fast_tanh(sx[1][h8 + j] + epj) * vj;
      s2 += fast_tanh(sx[2][h8 + j] + epj) * vj;
      s3 += fast_tanh(sx[3][h8 + j] + epj) * vj;
    }
#pragma unroll
    for (int off = 32; off; off >>= 1) {
      s0 += __shfl_down(s0, off);
      s1 += __shfl_down(s1, off);
      s2 += __shfl_down(s2, off);
      s3 += __shfl_down(s3, off);
    }
    if (lane == 0) {
      size_t base = ((size_t)(t2g * 4) * BB + b) * T1N + t1;
      e[base]                 = s0;
      e[base + 1 * BB * T1N]  = s1;
      e[base + 2 * BB * T1N]  = s2;
      e[base + 3 * BB * T1N]  = s3;
    }
  }
}

__global__ __launch_bounds__(128) void k_softmax(const float* __restrict__ e, float* __restrict__ score,
                                                 float* __restrict__ out_last) {
  int row = blockIdx.x;
  int tid = threadIdx.x;
  float v = e[(size_t)row * T1N + tid];
  __shared__ float red[128];
  red[tid] = v; __syncthreads();
  for (int s = 64; s; s >>= 1) { if (tid < s) red[tid] = fmaxf(red[tid], red[tid + s]); __syncthreads(); }
  float mx = red[0]; __syncthreads();
  float p = __expf(v - mx);
  red[tid] = p; __syncthreads();
  for (int s = 64; s; s >>= 1) { if (tid < s) red[tid] += red[tid + s]; __syncthreads(); }
  float sc = p / red[0];
  score[(size_t)row * T1N + tid] = sc;
  if ((row >> 5) == T2N - 1) out_last[tid * BB + (row & 31)] = sc;
}

__global__ __launch_bounds__(256) void k_attv(const float* __restrict__ enc, const float* __restrict__ score,
                                              ushort* __restrict__ ginB) {
  int t2g = blockIdx.x >> 5;
  int b   = blockIdx.x & 31;
  __shared__ float ssc[8][T1N];
  int tid = threadIdx.x;
  for (int i = tid; i < 8 * T1N; i += 256) {
    int j = i >> 7, t1 = i & 127;
    ssc[j][t1] = score[((size_t)(t2g * 8 + j) * BB + b) * T1N + t1];
  }
  __syncthreads();
  float a0[8] = {}, a1[8] = {};
  for (int t1 = 0; t1 < T1N; ++t1) {
    const float* er = enc + ((size_t)t1 * BB + b) * HH;
    float e0 = er[tid], e1 = er[tid + 256];
#pragma unroll
    for (int j = 0; j < 8; ++j) { a0[j] += e0 * ssc[j][t1]; a1[j] += e1 * ssc[j][t1]; }
  }
#pragma unroll
  for (int j = 0; j < 8; ++j) {
    size_t r = (size_t)(t2g * 8 + j) * BB + b;
    ginB[r * 1024 + 512 + tid]       = f2b(a0[j]);
    ginB[r * 1024 + 512 + tid + 256] = f2b(a1[j]);
  }
}

// ---------------- recurrence step kernels ----------------
// GRU elementwise pair helper: returns new h pair from packed bf16 gate pairs
__device__ __forceinline__ void gru_pair(uint gr, uint gz, uint gn, uint hr, uint hz, uint hn,
                                         float hold0, float hold1, float& o0, float& o1) {
  float r0 = fsig(blo(gr) + blo(hr));
  float r1 = fsig(bhi(gr) + bhi(hr));
  float z0 = fsig(blo(gz) + blo(hz));
  float z1 = fsig(bhi(gz) + bhi(hz));
  float n0 = fast_tanh(blo(gn) + r0 * blo(hn));
  float n1 = fast_tanh(bhi(gn) + r1 * bhi(hn));
  o0 = (1.f - z0) * n0 + z0 * hold0;
  o1 = (1.f - z1) * n1 + z1 * hold1;
}

// k_stepA(t): [t>0] h1(t-1) = GRU(gi1x, gh1x_in, h1_in) (redundant per block; designated global write)
//             then gh0(t) = h0(t-1) @ Whh0^T + bhh0 ; gh1(t) = h1(t-1) @ Whh1^T + bhh1  (bf16 out)
// grid 48 x 256; block owns 32 n-rows.
__global__ __launch_bounds__(256) void k_stepA(
    int t,
    const ushort* __restrict__ Whh0B, const ushort* __restrict__ Whh1B,
    const float* __restrict__ bhh0, const float* __restrict__ bhh1,
    const ushort* __restrict__ gi1x, const ushort* __restrict__ gh1x_in,
    const float* __restrict__ h1_in,     // fp32 h1(t-2) (state+16384 for t<=1)
    const float* __restrict__ state1,    // state+16384 (staging at t==0)
    const ushort* __restrict__ h0B_in,   // bf16 h0(t-1) (stateB at t==0)
    ushort* __restrict__ gh0x_out, ushort* __restrict__ gh1x_out,
    float* __restrict__ h1_out, ushort* __restrict__ ys_out) {
  __shared__ ushort sH1[32 * 520];
  const int tid = threadIdx.x;
  const int blk = blockIdx.x;

  if (t == 0) {
    for (int i = tid; i < 16384; i += 256) {
      int b = i >> 9, k = i & 511;
      sH1[b * 520 + k] = f2b(state1[i]);
    }
  } else {
    const int k0 = tid * 2;
#pragma unroll 4
    for (int b = 0; b < 32; ++b) {
      const ushort* gi = gi1x + b * 1536 + k0;
      const ushort* gh = gh1x_in + b * 1536 + k0;
      uint gir = *(const uint*)(gi);
      uint giz = *(const uint*)(gi + 512);
      uint gin = *(const uint*)(gi + 1024);
      uint hr  = *(const uint*)(gh);
      uint hz  = *(const uint*)(gh + 512);
      uint hn  = *(const uint*)(gh + 1024);
      float2 hold = *(const float2*)(h1_in + b * 512 + k0);
      float o0, o1;
      gru_pair(gir, giz, gin, hr, hz, hn, hold.x, hold.y, o0, o1);
      uint hb = (uint)f2b(o0) | ((uint)f2b(o1) << 16);
      *(uint*)(&sH1[b * 520 + k0]) = hb;
      if (blk == b) {
        *(float2*)(h1_out + b * 512 + k0) = make_float2(o0, o1);
        *(uint*)(ys_out + b * 512 + k0) = hb;
      }
    }
  }
  __syncthreads();

  const int lane = tid & 63, wave = tid >> 6;
  const int bt = wave & 1, nt = wave >> 1;
  const int m16 = lane & 15, quad = lane >> 4;
  const int nrow = blk * 32 + nt * 16 + m16;

  f32x4 acc0 = {0.f, 0.f, 0.f, 0.f}, acc1 = {0.f, 0.f, 0.f, 0.f};
  const ushort* Arow0 = h0B_in + (bt * 16 + m16) * 512 + quad * 8;
  const ushort* Brow0 = Whh0B + (size_t)nrow * 512 + quad * 8;
  const ushort* Brow1 = Whh1B + (size_t)nrow * 512 + quad * 8;
  const ushort* sArow1 = &sH1[(bt * 16 + m16) * 520 + quad * 8];
#pragma unroll 4
  for (int kc = 0; kc < 16; ++kc) {
    short8 a0 = *(const short8*)(Arow0 + kc * 32);
    short8 b0 = *(const short8*)(Brow0 + kc * 32);
    acc0 = __builtin_amdgcn_mfma_f32_16x16x32_bf16(a0, b0, acc0, 0, 0, 0);
    short8 a1 = *(const short8*)(sArow1 + kc * 32);
    short8 b1 = *(const short8*)(Brow1 + kc * 32);
    acc1 = __builtin_amdgcn_mfma_f32_16x16x32_bf16(a1, b1, acc1, 0, 0, 0);
  }
  float bv0 = bhh0[nrow], bv1 = bhh1[nrow];
  int brow = bt * 16 + quad * 4;
#pragma unroll
  for (int r = 0; r < 4; ++r) {
    gh0x_out[(brow + r) * 1536 + nrow] = f2b(acc0[r] + bv0);
    gh1x_out[(brow + r) * 1536 + nrow] = f2b(acc1[r] + bv1);
  }
}

// k_stepB(t): h0(t) = GRU(gi0B[t], gh0x, h0_in) (redundant; designated write fp32+bf16)
//             then gi1(t) = h0(t) @ Wih1^T + bih1  (bf16 out)
__global__ __launch_bounds__(256) void k_stepB(
    int t,
    const ushort* __restrict__ Wih1B, const float* __restrict__ bih1,
    const ushort* __restrict__ gi0B, const ushort* __restrict__ gh0x,
    const float* __restrict__ h0_in,     // fp32 h0(t-1) (state at t==0)
    float* __restrict__ h0_out, ushort* __restrict__ h0B_out,
    ushort* __restrict__ gi1x_out) {
  __shared__ ushort sH0[32 * 520];
  const int tid = threadIdx.x;
  const int blk = blockIdx.x;
  const ushort* gi0t = gi0B + (size_t)t * 32 * 1536;

  const int k0 = tid * 2;
#pragma unroll 4
  for (int b = 0; b < 32; ++b) {
    const ushort* gi = gi0t + b * 1536 + k0;
    const ushort* gh = gh0x + b * 1536 + k0;
    uint gir = *(const uint*)(gi);
    uint giz = *(const uint*)(gi + 512);
    uint gin = *(const uint*)(gi + 1024);
    uint hr  = *(const uint*)(gh);
    uint hz  = *(const uint*)(gh + 512);
    uint hn  = *(const uint*)(gh + 1024);
    float2 hold = *(const float2*)(h0_in + b * 512 + k0);
    float o0, o1;
    gru_pair(gir, giz, gin, hr, hz, hn, hold.x, hold.y, o0, o1);
    uint hb = (uint)f2b(o0) | ((uint)f2b(o1) << 16);
    *(uint*)(&sH0[b * 520 + k0]) = hb;
    if (blk == b) {
      *(float2*)(h0_out + b * 512 + k0) = make_float2(o0, o1);
      *(uint*)(h0B_out + b * 512 + k0) = hb;
    }
  }
  __syncthreads();

  const int lane = tid & 63, wave = tid >> 6;
  const int bt = wave & 1, nt = wave >> 1;
  const int m16 = lane & 15, quad = lane >> 4;
  const int nrow = blk * 32 + nt * 16 + m16;

  f32x4 acc = {0.f, 0.f, 0.f, 0.f};
  const ushort* Brow = Wih1B + (size_t)nrow * 512 + quad * 8;
  const ushort* sArow = &sH0[(bt * 16 + m16) * 520 + quad * 8];
#pragma unroll 4
  for (int kc = 0; kc < 16; ++kc) {
    short8 a = *(const short8*)(sArow + kc * 32);
    short8 b = *(const short8*)(Brow + kc * 32);
    acc = __builtin_amdgcn_mfma_f32_16x16x32_bf16(a, b, acc, 0, 0, 0);
  }
  float bv = bih1[nrow];
  int brow = bt * 16 + quad * 4;
#pragma unroll
  for (int r = 0; r < 4; ++r)
    gi1x_out[(brow + r) * 1536 + nrow] = f2b(acc[r] + bv);
}

// final: h1(63), ys[63], out_h
__global__ __launch_bounds__(256) void k_final(
    const ushort* __restrict__ gi1x, const ushort* __restrict__ gh1x,
    const float* __restrict__ h1_in, const float* __restrict__ h0_fin,
    float* __restrict__ out_h, ushort* __restrict__ ys_out) {
  const int b = blockIdx.x;
  const int k0 = threadIdx.x * 2;
  const ushort* gi = gi1x + b * 1536 + k0;
  const ushort* gh = gh1x + b * 1536 + k0;
  uint gir = *(const uint*)(gi);
  uint giz = *(const uint*)(gi + 512);
  uint gin = *(const uint*)(gi + 1024);
  uint hr  = *(const uint*)(gh);
  uint hz  = *(const uint*)(gh + 512);
  uint hn  = *(const uint*)(gh + 1024);
  float2 hold = *(const float2*)(h1_in + b * 512 + k0);
  float o0, o1;
  gru_pair(gir, giz, gin, hr, hz, hn, hold.x, hold.y, o0, o1);
  *(uint*)(ys_out + b * 512 + k0) = (uint)f2b(o0) | ((uint)f2b(o1) << 16);
  out_h[16384 + b * 512 + k0]     = o0;
  out_h[16384 + b * 512 + k0 + 1] = o1;
  float2 h0p = *(const float2*)(h0_fin + b * 512 + k0);
  *(float2*)(out_h + b * 512 + k0) = h0p;
}

// ---------------- launch ----------------
extern "C" void kernel_launch(void* const* d_in, const int* in_sizes, int n_in,
                              void* d_out, int out_size, void* d_ws, size_t ws_size,
                              hipStream_t stream) {
  const int*   toks  = (const int*)d_in[0];
  const float* state = (const float*)d_in[1];
  const float* enc   = (const float*)d_in[2];
  const float* emb   = (const float*)d_in[3];
  const float* wa_W  = (const float*)d_in[4];
  const float* wa_b  = (const float*)d_in[5];
  const float* va    = (const float*)d_in[6];
  const float* b_ih0 = (const float*)d_in[9];
  const float* b_hh0 = (const float*)d_in[10];
  const float* b_ih1 = (const float*)d_in[13];
  const float* b_hh1 = (const float*)d_in[14];
  const float* out_W = (const float*)d_in[15];
  const float* out_b = (const float*)d_in[16];
  const float* W_ih0 = (const float*)d_in[7];
  const float* W_hh0 = (const float*)d_in[8];
  const float* W_ih1 = (const float*)d_in[11];
  const float* W_hh1 = (const float*)d_in[12];

  float* y_out  = (float*)d_out;
  float* h_out  = y_out + (size_t)T2N * BB * VV;
  float* ls_out = h_out + 2 * BB * HH;

  char* ws = (char*)d_ws;
  size_t off = 0;
  auto alloc = [&](size_t bytes) -> void* {
    void* p = ws + off;
    off += (bytes + 255) & ~(size_t)255;
    return p;
  };
  ushort* encB   = (ushort*)alloc((size_t)T1N * BB * HH * 2);
  ushort* ginB   = (ushort*)alloc((size_t)T2N * BB * 2 * HH * 2);
  ushort* WeB    = (ushort*)alloc((size_t)HH * HH * 2);
  ushort* WxB    = (ushort*)alloc((size_t)HH * HH * 2);
  ushort* Wih0B  = (ushort*)alloc((size_t)3 * HH * 2 * HH * 2);
  ushort* Whh0B  = (ushort*)alloc((size_t)3 * HH * HH * 2);
  ushort* Wih1B  = (ushort*)alloc((size_t)3 * HH * HH * 2);
  ushort* Whh1B  = (ushort*)alloc((size_t)3 * HH * HH * 2);
  ushort* outWB  = (ushort*)alloc((size_t)VV * HH * 2);
  ushort* stateB = (ushort*)alloc((size_t)BB * HH * 2);
  float* encproj = (float*)alloc((size_t)T1N * BB * HH * 4);
  float* xproj   = (float*)alloc((size_t)T2N * BB * HH * 4);
  float* eM      = (float*)alloc((size_t)T2N * BB * T1N * 4);
  float* score   = (float*)alloc((size_t)T2N * BB * T1N * 4);
  ushort* gi0B   = (ushort*)alloc((size_t)T2N * BB * 3 * HH * 2);
  ushort* gh0x   = (ushort*)alloc((size_t)BB * 3 * HH * 2);
  ushort* gh1buf0 = (ushort*)alloc((size_t)BB * 3 * HH * 2);
  ushort* gh1buf1 = (ushort*)alloc((size_t)BB * 3 * HH * 2);
  ushort* gi1x   = (ushort*)alloc((size_t)BB * 3 * HH * 2);
  float* h0buf0  = (float*)alloc((size_t)BB * HH * 4);
  float* h0buf1  = (float*)alloc((size_t)BB * HH * 4);
  float* h1buf0  = (float*)alloc((size_t)BB * HH * 4);
  float* h1buf1  = (float*)alloc((size_t)BB * HH * 4);
  ushort* h0bufB0 = (ushort*)alloc((size_t)BB * HH * 2);
  ushort* h0bufB1 = (ushort*)alloc((size_t)BB * HH * 2);
  ushort* ysB    = (ushort*)alloc((size_t)T2N * BB * HH * 2);

  ushort* gh1buf[2]  = {gh1buf0, gh1buf1};
  float*  h0buf[2]   = {h0buf0, h0buf1};
  float*  h1buf[2]   = {h1buf0, h1buf1};
  ushort* h0bufB[2]  = {h0bufB0, h0bufB1};

  // preamble
  k_cvt<<<VV * HH / 1024, 256, 0, stream>>>(out_W, outWB, VV * HH);
  k_cvt<<<T1N * BB * HH / 1024, 256, 0, stream>>>(enc, encB, T1N * BB * HH);
  k_cvt<<<3 * HH * 2 * HH / 1024, 256, 0, stream>>>(W_ih0, Wih0B, 3 * HH * 2 * HH);
  k_cvt<<<3 * HH * HH / 1024, 256, 0, stream>>>(W_hh0, Whh0B, 3 * HH * HH);
  k_cvt<<<3 * HH * HH / 1024, 256, 0, stream>>>(W_ih1, Wih1B, 3 * HH * HH);
  k_cvt<<<3 * HH * HH / 1024, 256, 0, stream>>>(W_hh1, Whh1B, 3 * HH * HH);
  k_cvt<<<BB * HH / 1024, 256, 0, stream>>>(state, stateB, BB * HH);
  k_cvt_wa<<<2 * HH * HH / 1024, 256, 0, stream>>>(wa_W, WxB, WeB);
  k_embed<<<T2N * BB * HH / 1024, 256, 0, stream>>>(toks, emb, ginB);

  k_gemm<<<dim3(HH / 128, T1N * BB / 128), 256, 0, stream>>>(encB, HH, WeB, wa_b, encproj, HH, HH);
  k_gemm<<<dim3(HH / 128, T2N * BB / 128), 256, 0, stream>>>(ginB, 2 * HH, WxB, nullptr, xproj, HH, HH);

  k_scores<<<512, 256, 0, stream>>>(xproj, encproj, va, eM);
  k_softmax<<<T2N * BB, 128, 0, stream>>>(eM, score, ls_out);
  k_attv<<<256, 256, 0, stream>>>(enc, score, ginB);

  k_gemm_b16<<<dim3(3 * HH / 128, T2N * BB / 128), 256, 0, stream>>>(ginB, 2 * HH, Wih0B, b_ih0, gi0B, 3 * HH, 2 * HH);

  // recurrence: 64 x (A,B)
  for (int t = 0; t < T2N; ++t) {
    const float*  h1_in  = (t <= 1) ? (state + BB * HH) : h1buf[t & 1];
    const ushort* h0B_in = (t == 0) ? stateB : h0bufB[(t + 1) & 1];
    ushort* ys_prev = (t == 0) ? ysB : (ysB + (size_t)(t - 1) * BB * HH);
    k_stepA<<<48, 256, 0, stream>>>(t, Whh0B, Whh1B, b_hh0, b_hh1,
                                    gi1x, gh1buf[(t + 1) & 1],
                                    h1_in, state + BB * HH, h0B_in,
                                    gh0x, gh1buf[t & 1],
                                    h1buf[(t + 1) & 1], ys_prev);
    const float* h0_in = (t == 0) ? state : h0buf[(t + 1) & 1];
    k_stepB<<<48, 256, 0, stream>>>(t, Wih1B, b_ih1, gi0B, gh0x, h0_in,
                                    h0buf[t & 1], h0bufB[t & 1], gi1x);
  }
  k_final<<<32, 256, 0, stream>>>(gi1x, gh1buf[1], h1buf[0], h0buf[1],
                                  h_out, ysB + (size_t)63 * BB * HH);

  // y = ys @ out_W^T + out_b
  k_gemm<<<dim3(VV / 128, T2N * BB / 128), 256, 0, stream>>>(ysB, HH, outWB, out_b, y_out, VV, HH);
}